// Round 3
// baseline (201.108 us; speedup 1.0000x reference)
//
#include <hip/hip_runtime.h>

// MACD: EMA_slow(x) - EMA_fast(x) over time axis.
// x: [B=4096, T=2048, F=8] fp32 contiguous. Block per b, thread per 8-step
// t-chunk (all 8 features). Low-register variant: phase 1 streams x to build
// chunk-end EMAs only; Kogge-Stone scan composes carries; phase 2 RE-READS x
// (cache-warm) and re-runs the exact recurrence from the scanned carry-in.

#define T_LEN 2048
#define FDIM 8
#define CHUNK 8
#define NCHUNK (T_LEN / CHUNK)   // 256 == blockDim.x
#define NSER (2 * FDIM)          // 16 series: (f, slow/fast)

__device__ __forceinline__ float pow8(float v) {
    float v2 = v * v;
    float v4 = v2 * v2;
    return v4 * v4;
}

__global__ __launch_bounds__(NCHUNK, 4)
void macd_kernel(const float* __restrict__ x, float* __restrict__ out) {
    const float AS  = (float)(2.0 / 27.0);   // alpha slow (N=26)
    const float AF  = (float)(2.0 / 13.0);   // alpha fast (N=12)
    const float OMS = 1.0f - AS;
    const float OMF = 1.0f - AF;

    const int b = blockIdx.x;
    const int c = threadIdx.x;               // chunk index 0..255

    const float* xb = x   + (size_t)b * (T_LEN * FDIM);
    float*       ob = out + (size_t)b * (T_LEN * FDIM);
    const float4* xv = reinterpret_cast<const float4*>(xb + c * CHUNK * FDIM);

    // ---- Phase 1: stream x, build chunk-end zero-init EMAs (p[16] only) ---
    float p[NSER];                            // p[2f]=slow, p[2f+1]=fast
#pragma unroll
    for (int s = 0; s < NSER; ++s) p[s] = 0.f;

#pragma unroll
    for (int i = 0; i < CHUNK; ++i) {
        float4 lo = xv[i * 2 + 0];
        float4 hi = xv[i * 2 + 1];
        float xx[FDIM] = {lo.x, lo.y, lo.z, lo.w, hi.x, hi.y, hi.z, hi.w};
#pragma unroll
        for (int f = 0; f < FDIM; ++f) {
            p[2 * f + 0] = AS * xx[f] + OMS * p[2 * f + 0];
            p[2 * f + 1] = AF * xx[f] + OMF * p[2 * f + 1];
        }
    }

    // Seed y_{-1} = x0 into chunk 0's partial (reproduces y0 = x0 exactly).
    if (c == 0) {
        const float DS = pow8(OMS), DF = pow8(OMF);
#pragma unroll
        for (int f = 0; f < FDIM; ++f) {
            float x0 = xb[f];                 // L1 hit (just loaded)
            p[2 * f + 0] += DS * x0;
            p[2 * f + 1] += DF * x0;
        }
    }

    // ---- Kogge-Stone inclusive scan over 256 chunks (const multipliers) ---
    __shared__ float sc[NSER][NCHUNK];        // 16 KiB; stride-1 across lanes
    float Ms = pow8(OMS), Mf = pow8(OMF);
#pragma unroll
    for (int off = 1; off < NCHUNK; off <<= 1) {
#pragma unroll
        for (int s = 0; s < NSER; ++s) sc[s][c] = p[s];
        __syncthreads();
        if (c >= off) {
#pragma unroll
            for (int s = 0; s < NSER; ++s)
                p[s] += ((s & 1) ? Mf : Ms) * sc[s][c - off];
        }
        Ms *= Ms; Mf *= Mf;
        __syncthreads();
    }
#pragma unroll
    for (int s = 0; s < NSER; ++s) sc[s][c] = p[s];
    __syncthreads();

    // ---- Carry-in = scanned EMA value at end of previous chunk ------------
    float ys[FDIM], yf[FDIM];
#pragma unroll
    for (int f = 0; f < FDIM; ++f) {
        if (c == 0) { ys[f] = yf[f] = xb[f]; }
        else        { ys[f] = sc[2 * f + 0][c - 1]; yf[f] = sc[2 * f + 1][c - 1]; }
    }

    // ---- Phase 2: re-read x (cache-warm), run exact recurrence, write -----
    float4* ov = reinterpret_cast<float4*>(ob + c * CHUNK * FDIM);
#pragma unroll
    for (int i = 0; i < CHUNK; ++i) {
        float4 lo = xv[i * 2 + 0];
        float4 hi = xv[i * 2 + 1];
        float xx[FDIM] = {lo.x, lo.y, lo.z, lo.w, hi.x, hi.y, hi.z, hi.w};
        float o[FDIM];
#pragma unroll
        for (int f = 0; f < FDIM; ++f) {
            ys[f] = AS * xx[f] + OMS * ys[f];
            yf[f] = AF * xx[f] + OMF * yf[f];
            o[f] = ys[f] - yf[f];
        }
        float4 olo = {o[0], o[1], o[2], o[3]};
        float4 ohi = {o[4], o[5], o[6], o[7]};
        ov[i * 2 + 0] = olo;
        ov[i * 2 + 1] = ohi;
    }
}

extern "C" void kernel_launch(void* const* d_in, const int* in_sizes, int n_in,
                              void* d_out, int out_size, void* d_ws, size_t ws_size,
                              hipStream_t stream) {
    (void)n_in; (void)d_ws; (void)ws_size; (void)out_size;
    const float* x = (const float*)d_in[0];
    float* out = (float*)d_out;
    const int B = in_sizes[0] / (T_LEN * FDIM);   // 4096
    macd_kernel<<<dim3(B), dim3(NCHUNK), 0, stream>>>(x, out);
}

// Round 4
// 108.685 us; speedup vs baseline: 1.8504x; 1.8504x over previous
//
#include <hip/hip_runtime.h>

// MACD: EMA_slow(x) - EMA_fast(x) over time axis.
// x: [B=4096, T=2048, F=8] fp32 contiguous. Block per row b.
// Full 64 KB row staged in LDS with XOR swizzle so ALL global traffic is
// lane-contiguous float4 (fixes the 256B-stride gather of R1-R3).
// Scan: intra-wave shfl Kogge-Stone + cross-wave combine (3 barriers total).

#define T_LEN 2048
#define FDIM 8
#define CHUNK 8
#define NTHR 256
#define NF4 (T_LEN * FDIM / 4)   // 4096 float4 slots per row

__device__ __forceinline__ float pow8(float v) {
    float v2 = v * v;
    float v4 = v2 * v2;
    return v4 * v4;
}

// involution on float4-slot index: flips bits 0-2 keyed on bits 4-6.
__device__ __forceinline__ int swz(int g) { return g ^ ((g >> 4) & 7); }

__global__ __launch_bounds__(NTHR, 2)
void macd_kernel(const float* __restrict__ x, float* __restrict__ out) {
    const float AS  = (float)(2.0 / 27.0);   // alpha slow (N=26)
    const float AF  = (float)(2.0 / 13.0);   // alpha fast (N=12)
    const float OMS = 1.0f - AS;
    const float OMF = 1.0f - AF;
    const float DS  = pow8(OMS);             // per-chunk decay (8 steps)
    const float DF  = pow8(OMF);

    __shared__ float4 xb4[NF4];              // 64 KiB row tile (swizzled)
    __shared__ float  W[4][16];              // wave-end partials

    const int b = blockIdx.x;
    const int j = threadIdx.x;               // 0..255
    const int w = j >> 6;                    // wave id
    const int l = j & 63;                    // lane id

    const float4* xg = reinterpret_cast<const float4*>(x   + (size_t)b * T_LEN * FDIM);
    float4*       og = reinterpret_cast<float4*>      (out + (size_t)b * T_LEN * FDIM);

    // ---- Stage: coalesced global float4 reads -> swizzled LDS writes ------
#pragma unroll
    for (int k = 0; k < 16; ++k) {
        int g = k * NTHR + j;                // lane-contiguous per wave-instr
        xb4[swz(g)] = xg[g];
    }
    __syncthreads();

    // ---- Phase 1: per-chunk zero-init EMA partials (thread c = chunk c) ---
    const int c   = j;
    const int key = c & 7;                   // swz key for this chunk's slots
    float p[16];                             // p[2f]=slow, p[2f+1]=fast
#pragma unroll
    for (int s = 0; s < 16; ++s) p[s] = 0.f;

#pragma unroll
    for (int t = 0; t < CHUNK; ++t) {
        float4 lo = xb4[16 * c + ((2 * t    ) ^ key)];
        float4 hi = xb4[16 * c + ((2 * t + 1) ^ key)];
        float xx[FDIM] = {lo.x, lo.y, lo.z, lo.w, hi.x, hi.y, hi.z, hi.w};
#pragma unroll
        for (int f = 0; f < FDIM; ++f) {
            p[2 * f + 0] = AS * xx[f] + OMS * p[2 * f + 0];
            p[2 * f + 1] = AF * xx[f] + OMF * p[2 * f + 1];
        }
    }

    // Seed y_{-1} = x0 folded into chunk 0's partial (exact y0 = x0 chain).
    const float* xs = reinterpret_cast<const float*>(xb4);   // slots 0,1 swz=id
    if (j == 0) {
#pragma unroll
        for (int f = 0; f < FDIM; ++f) {
            float x0 = xs[f];
            p[2 * f + 0] += DS * x0;
            p[2 * f + 1] += DF * x0;
        }
    }

    // ---- Intra-wave inclusive Kogge-Stone scan (no barriers) --------------
    float Ms = DS, Mf = DF;
#pragma unroll
    for (int off = 1; off < 64; off <<= 1) {
#pragma unroll
        for (int s = 0; s < 16; ++s) {
            float tv = __shfl_up(p[s], (unsigned)off, 64);
            if (l >= off) p[s] += ((s & 1) ? Mf : Ms) * tv;
        }
        Ms *= Ms; Mf *= Mf;                  // ends as D^64 (wave decay)
    }

    // Exclusive-within-wave value (lane l-1's inclusive scan).
    float qe[16];
#pragma unroll
    for (int s = 0; s < 16; ++s) qe[s] = __shfl_up(p[s], 1u, 64);

    // ---- Cross-wave combine (1 barrier) -----------------------------------
    if (l == 63) {
#pragma unroll
        for (int s = 0; s < 16; ++s) W[w][s] = p[s];
    }
    __syncthreads();

    float Sp[16];                            // scanned carry at end of wave w-1
#pragma unroll
    for (int s = 0; s < 16; ++s) Sp[s] = 0.f;
    for (int v = 0; v < w; ++v) {            // w <= 3 iterations, wave-uniform
#pragma unroll
        for (int s = 0; s < 16; ++s)
            Sp[s] = W[v][s] + ((s & 1) ? Mf : Ms) * Sp[s];
    }

    // Per-lane D^l via binary powering (exact multiplies).
    float Dls = 1.f, Dlf = 1.f, ms2 = DS, mf2 = DF;
#pragma unroll
    for (int bit = 0; bit < 6; ++bit) {
        if ((l >> bit) & 1) { Dls *= ms2; Dlf *= mf2; }
        ms2 *= ms2; mf2 *= mf2;
    }

    // Carry-in to chunk c = full scan at chunk c-1.
    float ys[FDIM], yf[FDIM];
#pragma unroll
    for (int f = 0; f < FDIM; ++f) {
        float cs = (l == 0) ? Sp[2 * f + 0] : qe[2 * f + 0] + Dls * Sp[2 * f + 0];
        float cf = (l == 0) ? Sp[2 * f + 1] : qe[2 * f + 1] + Dlf * Sp[2 * f + 1];
        ys[f] = cs; yf[f] = cf;
    }
    if (j == 0) {                            // true seed for chunk 0: y_{-1}=x0
#pragma unroll
        for (int f = 0; f < FDIM; ++f) { ys[f] = xs[f]; yf[f] = xs[f]; }
    }

    // ---- Phase 2: exact recurrence from carry, write out into LDS in place
#pragma unroll
    for (int t = 0; t < CHUNK; ++t) {
        int slo = 16 * c + ((2 * t    ) ^ key);
        int shi = 16 * c + ((2 * t + 1) ^ key);
        float4 lo = xb4[slo];
        float4 hi = xb4[shi];
        float xx[FDIM] = {lo.x, lo.y, lo.z, lo.w, hi.x, hi.y, hi.z, hi.w};
        float o[FDIM];
#pragma unroll
        for (int f = 0; f < FDIM; ++f) {
            ys[f] = AS * xx[f] + OMS * ys[f];
            yf[f] = AF * xx[f] + OMF * yf[f];
            o[f] = ys[f] - yf[f];
        }
        float4 olo = {o[0], o[1], o[2], o[3]};
        float4 ohi = {o[4], o[5], o[6], o[7]};
        xb4[slo] = olo;
        xb4[shi] = ohi;
    }
    __syncthreads();

    // ---- Store: swizzled LDS reads -> coalesced global float4 stores ------
#pragma unroll
    for (int k = 0; k < 16; ++k) {
        int g = k * NTHR + j;
        og[g] = xb4[swz(g)];
    }
}

extern "C" void kernel_launch(void* const* d_in, const int* in_sizes, int n_in,
                              void* d_out, int out_size, void* d_ws, size_t ws_size,
                              hipStream_t stream) {
    (void)n_in; (void)d_ws; (void)ws_size; (void)out_size;
    const float* x = (const float*)d_in[0];
    float* out = (float*)d_out;
    const int B = in_sizes[0] / (T_LEN * FDIM);   // 4096
    macd_kernel<<<dim3(B), dim3(NTHR), 0, stream>>>(x, out);
}